// Round 16
// baseline (482.347 us; speedup 1.0000x reference)
//
#include <hip/hip_runtime.h>
#include <hip/hip_bf16.h>

#define N_NODES 100000
#define N_EDGES 600000
#define N_GRAPHS 64
#define D 128

#define NBLK_SCAN ((N_NODES + 255) / 256)  // 391

typedef __attribute__((ext_vector_type(8))) short short8v;
typedef __attribute__((ext_vector_type(4))) float float4v;

__device__ __forceinline__ unsigned short f2bf(float f) {
    unsigned int u = __float_as_uint(f);
    return (unsigned short)((u + 0x7FFF + ((u >> 16) & 1)) >> 16);  // RNE
}
__device__ __forceinline__ float bf2f(unsigned short h) {
    return __uint_as_float(((unsigned int)h) << 16);
}

// ---------------- CSR build ----------------

__global__ void count_deg_k(const int* __restrict__ col, int* __restrict__ cnt) {
    int e = blockIdx.x * blockDim.x + threadIdx.x;
    if (e < N_EDGES) atomicAdd(&cnt[col[e]], 1);
}

__global__ __launch_bounds__(256) void partial_k(const int* __restrict__ cnt,
                                                 int* __restrict__ psum) {
    int i = blockIdx.x * 256 + threadIdx.x;
    int v = (i < N_NODES) ? cnt[i] : 0;
#pragma unroll
    for (int d = 32; d > 0; d >>= 1) v += __shfl_down(v, d, 64);
    __shared__ int ws[4];
    if ((threadIdx.x & 63) == 0) ws[threadIdx.x >> 6] = v;
    __syncthreads();
    if (threadIdx.x == 0) psum[blockIdx.x] = ws[0] + ws[1] + ws[2] + ws[3];
}

__global__ __launch_bounds__(512) void scanpart_k(int* __restrict__ psum) {
    __shared__ int ls[512];
    int t = threadIdx.x;
    int v = (t < NBLK_SCAN) ? psum[t] : 0;
    ls[t] = v;
    __syncthreads();
    for (int d = 1; d < 512; d <<= 1) {
        int u = (t >= d) ? ls[t - d] : 0;
        __syncthreads();
        ls[t] += u;
        __syncthreads();
    }
    if (t < NBLK_SCAN) psum[t] = ls[t] - v;  // exclusive
}

__global__ __launch_bounds__(256) void scan_scatter_k(const int* __restrict__ cnt,
                                                      const int* __restrict__ psum,
                                                      int* __restrict__ start) {
    int b = blockIdx.x, t = threadIdx.x;
    int i = b * 256 + t;
    int v = (i < N_NODES) ? cnt[i] : 0;
    __shared__ int ls[256];
    ls[t] = v;
    __syncthreads();
    for (int d = 1; d < 256; d <<= 1) {
        int u = (t >= d) ? ls[t - d] : 0;
        __syncthreads();
        ls[t] += u;
        __syncthreads();
    }
    int incl = ls[t];
    int off = psum[b];
    if (i < N_NODES) start[i] = off + incl - v;
    if (i == N_NODES - 1) start[N_NODES] = off + incl;
}

__global__ void fill_csr_k(const int* __restrict__ row, const int* __restrict__ col,
                           const int* __restrict__ start, int* __restrict__ fill,
                           int* __restrict__ esrc) {
    int e = blockIdx.x * blockDim.x + threadIdx.x;
    if (e < N_EDGES) {
        int c = col[e];
        int p = atomicAdd(&fill[c], 1);
        esrc[start[c] + p] = row[e];
    }
}

// ---------------- graph segment bounds (batch is sorted) ----------------

__global__ __launch_bounds__(128) void bounds_k(const int* __restrict__ batch,
                                                int* __restrict__ gstart) {
    int g = threadIdx.x;
    if (g > N_GRAPHS) return;
    int lo = 0, hi = N_NODES;
    while (lo < hi) {
        int mid = (lo + hi) >> 1;
        if (batch[mid] < g) lo = mid + 1; else hi = mid;
    }
    gstart[g] = lo;
}

// ---------------- f32 -> (bf16 hi, bf16 lo) split (weights only) ----------------

__global__ __launch_bounds__(256) void split_k(const float* __restrict__ in,
                                               unsigned short* __restrict__ hi,
                                               unsigned short* __restrict__ lo, int n4) {
    int i = blockIdx.x * 256 + threadIdx.x;
    if (i >= n4) return;
    float4 v = reinterpret_cast<const float4*>(in)[i];
    ushort4 h, l;
    h.x = f2bf(v.x); l.x = f2bf(v.x - bf2f(h.x));
    h.y = f2bf(v.y); l.y = f2bf(v.y - bf2f(h.y));
    h.z = f2bf(v.z); l.z = f2bf(v.z - bf2f(h.z));
    h.w = f2bf(v.w); l.w = f2bf(v.w - bf2f(h.w));
    reinterpret_cast<ushort4*>(hi)[i] = h;
    reinterpret_cast<ushort4*>(lo)[i] = l;
}

// ---------------- Fused layer: hout = relu(W * (h_i + sum_src h_src) + (1+deg)*b)
// h stays f32 end-to-end. Per block (256 thr): 64 output rows.
// Phase 1: half-wave-per-row f32 gather (contiguous 512B/row requests — the
//   measured-good aggregate_k pattern) + 4-edge ILP -> f32 LDS tile.
// Phase 2: wave-private 16 rows: A-fragments from LDS with in-register
//   hi/lo bf16 split (gemm_mfma_f32_k pattern); W hi/lo direct from L2;
//   4-term split-bf16 MFMA; de-scatter through own LDS slice; 512B row stores.

#define FTILE 64
#define FPITCH 132  // f32 words; 16B-aligned rows, odd/32 bank spread

__global__ __launch_bounds__(256) void fused_layer_k(
    const float* __restrict__ hin,
    const unsigned short* __restrict__ Whi, const unsigned short* __restrict__ Wlo,
    const float* __restrict__ bias,
    const int* __restrict__ start, const int* __restrict__ esrc,
    float* __restrict__ hout) {
    __shared__ float tile[FTILE * FPITCH];  // 33.8KB
    __shared__ float scnt[FTILE];
    const int tid = threadIdx.x;
    const int n0 = blockIdx.x * FTILE;

    // ---- phase 1: gather-aggregate ----
    {
        const int hw = tid >> 5, li = tid & 31;
        for (int it = 0; it < 8; ++it) {
            const int r = it * 8 + hw;
            const int node = n0 + r;
            float4 acc = make_float4(0.f, 0.f, 0.f, 0.f);
            int deg = 0;
            if (node < N_NODES) {
                const int s = start[node], e = start[node + 1];
                deg = e - s;
                acc = *reinterpret_cast<const float4*>(hin + ((size_t)node << 7) + 4 * li);
                int i = s;
                for (; i + 3 < e; i += 4) {
                    const float4 v0 = *reinterpret_cast<const float4*>(hin + (((size_t)esrc[i] << 7) + 4 * li));
                    const float4 v1 = *reinterpret_cast<const float4*>(hin + (((size_t)esrc[i + 1] << 7) + 4 * li));
                    const float4 v2 = *reinterpret_cast<const float4*>(hin + (((size_t)esrc[i + 2] << 7) + 4 * li));
                    const float4 v3 = *reinterpret_cast<const float4*>(hin + (((size_t)esrc[i + 3] << 7) + 4 * li));
                    acc.x += (v0.x + v1.x) + (v2.x + v3.x);
                    acc.y += (v0.y + v1.y) + (v2.y + v3.y);
                    acc.z += (v0.z + v1.z) + (v2.z + v3.z);
                    acc.w += (v0.w + v1.w) + (v2.w + v3.w);
                }
                for (; i < e; ++i) {
                    const float4 v = *reinterpret_cast<const float4*>(hin + (((size_t)esrc[i] << 7) + 4 * li));
                    acc.x += v.x; acc.y += v.y; acc.z += v.z; acc.w += v.w;
                }
            }
            *reinterpret_cast<float4*>(&tile[r * FPITCH + 4 * li]) = acc;
            if (li == 0) scnt[r] = (float)(1 + deg);
        }
    }
    __syncthreads();

    // ---- phase 2: per-wave 16 rows x 128 cols split-bf16 MFMA ----
    const int l = tid & 63, wv = tid >> 6;
    const int g = l >> 4, li16 = l & 15;

    float4v acc[8];
#pragma unroll
    for (int cg = 0; cg < 8; ++cg) acc[cg] = (float4v){0.f, 0.f, 0.f, 0.f};

#pragma unroll
    for (int kk = 0; kk < 4; ++kk) {
        const int k0 = kk * 32;
        // A fragment: LDS row wv*16+li16, cols k0+g*8..+7, split to hi/lo
        const float* tp = &tile[(wv * 16 + li16) * FPITCH + k0 + g * 8];
        float4 f0 = *reinterpret_cast<const float4*>(tp);
        float4 f1 = *reinterpret_cast<const float4*>(tp + 4);
        float fv[8] = {f0.x, f0.y, f0.z, f0.w, f1.x, f1.y, f1.z, f1.w};
        short8v ah, al;
#pragma unroll
        for (int j = 0; j < 8; ++j) {
            unsigned short h = f2bf(fv[j]);
            ah[j] = (short)h;
            al[j] = (short)f2bf(fv[j] - bf2f(h));
        }
#pragma unroll
        for (int cg = 0; cg < 8; ++cg) {
            const size_t wb = (size_t)(cg * 16 + li16) * D + g * 8 + k0;
            short8v wh = *reinterpret_cast<const short8v*>(Whi + wb);
            short8v wl = *reinterpret_cast<const short8v*>(Wlo + wb);
            acc[cg] = __builtin_amdgcn_mfma_f32_16x16x32_bf16(ah, wh, acc[cg], 0, 0, 0);
            acc[cg] = __builtin_amdgcn_mfma_f32_16x16x32_bf16(al, wh, acc[cg], 0, 0, 0);
            acc[cg] = __builtin_amdgcn_mfma_f32_16x16x32_bf16(ah, wl, acc[cg], 0, 0, 0);
            acc[cg] = __builtin_amdgcn_mfma_f32_16x16x32_bf16(al, wl, acc[cg], 0, 0, 0);
        }
    }

    // de-scatter C/D (row=g*4+r, col=cg*16+li16) into own tile slice
    // (wave-private rows; per-wave DS ordering makes this barrier-free)
#pragma unroll
    for (int cg = 0; cg < 8; ++cg)
#pragma unroll
        for (int r = 0; r < 4; ++r)
            tile[(wv * 16 + g * 4 + r) * FPITCH + cg * 16 + li16] = acc[cg][r];

    // epilogue: rows contiguous, +cnt*bias, relu, 512B row stores
    const int c4 = l & 31, rh = l >> 5;
    const float4 bv = *reinterpret_cast<const float4*>(&bias[4 * c4]);
#pragma unroll
    for (int it = 0; it < 8; ++it) {
        const int rowl = wv * 16 + it * 2 + rh;
        const int grow = n0 + rowl;
        if (grow < N_NODES) {
            float4 v = *reinterpret_cast<const float4*>(&tile[rowl * FPITCH + 4 * c4]);
            const float c = scnt[rowl];
            v.x = fmaxf(fmaf(c, bv.x, v.x), 0.f);
            v.y = fmaxf(fmaf(c, bv.y, v.y), 0.f);
            v.z = fmaxf(fmaf(c, bv.z, v.z), 0.f);
            v.w = fmaxf(fmaf(c, bv.w, v.w), 0.f);
            *reinterpret_cast<float4*>(&hout[(size_t)grow * D + 4 * c4]) = v;
        }
    }
}

// ---------------- Collapsed layer 4 + pool + head ----------------
// logit_g = (1/c_g) * sum_{i in g} [ s[i] + sum_{src->i} s[src] + (1+deg_i)*beta ] + bc
// where s[i] = h3[i] . v,  v = Wc @ W4,  beta = Wc . b4.

__global__ __launch_bounds__(128) void vbeta_k(const float* __restrict__ W4,
                                               const float* __restrict__ b4,
                                               const float* __restrict__ Wc,
                                               float* __restrict__ vbeta) {
    int k = threadIdx.x;
    float acc = 0.f;
    for (int j = 0; j < D; ++j) acc = fmaf(Wc[j], W4[j * D + k], acc);
    vbeta[k] = acc;
    __shared__ float red[128];
    red[k] = Wc[k] * b4[k];
    __syncthreads();
    for (int st = 64; st > 0; st >>= 1) {
        if (k < st) red[k] += red[k + st];
        __syncthreads();
    }
    if (k == 0) vbeta[D] = red[0];
}

__global__ __launch_bounds__(256) void matvec_k(const float* __restrict__ h,
                                                const float* __restrict__ vbeta,
                                                float* __restrict__ s) {
    int wid = threadIdx.x >> 6, lane = threadIdx.x & 63;
    int row = blockIdx.x * 4 + wid;
    const float2 hv = *reinterpret_cast<const float2*>(&h[(size_t)row * D + lane * 2]);
    const float2 vv = *reinterpret_cast<const float2*>(&vbeta[lane * 2]);
    float dot = fmaf(hv.x, vv.x, hv.y * vv.y);
#pragma unroll
    for (int d = 32; d > 0; d >>= 1) dot += __shfl_down(dot, d, 64);
    if (lane == 0) s[row] = dot;
}

__global__ __launch_bounds__(256) void sagg_k(const float* __restrict__ s,
                                              const int* __restrict__ start,
                                              const int* __restrict__ esrc,
                                              const float* __restrict__ vbeta,
                                              float* __restrict__ a) {
    int i = blockIdx.x * 256 + threadIdx.x;
    if (i >= N_NODES) return;
    int s0 = start[i], s1 = start[i + 1];
    float beta = vbeta[D];
    float acc = s[i] + (float)(1 + s1 - s0) * beta;
    for (int e = s0; e < s1; ++e) acc += s[esrc[e]];
    a[i] = acc;
}

__global__ __launch_bounds__(256) void spool_k(const float* __restrict__ a,
                                               const int* __restrict__ gstart,
                                               const float* __restrict__ bc,
                                               float* __restrict__ out) {
    int g = blockIdx.x;
    int lo = gstart[g], hi = gstart[g + 1];
    float acc = 0.f;
    for (int i = lo + threadIdx.x; i < hi; i += 256) acc += a[i];
    __shared__ float red[256];
    red[threadIdx.x] = acc;
    __syncthreads();
    for (int st = 128; st > 0; st >>= 1) {
        if (threadIdx.x < st) red[threadIdx.x] += red[threadIdx.x + st];
        __syncthreads();
    }
    if (threadIdx.x == 0) {
        float c = (float)max(hi - lo, 1);
        out[g] = 1.f / (1.f + expf(-(red[0] / c + bc[0])));
    }
}

// ---------------- Launch ----------------

extern "C" void kernel_launch(void* const* d_in, const int* in_sizes, int n_in,
                              void* d_out, int out_size, void* d_ws, size_t ws_size,
                              hipStream_t stream) {
    const float* x   = (const float*)d_in[0];
    const int* ei    = (const int*)d_in[1];
    const int* batch = (const int*)d_in[2];
    const float* W1  = (const float*)d_in[3];
    const float* b1  = (const float*)d_in[4];
    const float* W2  = (const float*)d_in[5];
    const float* b2  = (const float*)d_in[6];
    const float* W3  = (const float*)d_in[7];
    const float* b3  = (const float*)d_in[8];
    const float* W4  = (const float*)d_in[9];
    const float* b4  = (const float*)d_in[10];
    const float* Wc  = (const float*)d_in[11];
    const float* bc  = (const float*)d_in[12];
    float* out = (float*)d_out;

    const int* row = ei;             // sources
    const int* col = ei + N_EDGES;   // targets

    char* p = (char*)d_ws;
    float* hA = (float*)p;           p += (size_t)N_NODES * D * 4;   // 51.2 MB
    float* hB = (float*)p;           p += (size_t)N_NODES * D * 4;   // 51.2 MB
    unsigned short* whi = (unsigned short*)p; p += (size_t)D * D * 2;
    unsigned short* wlo = (unsigned short*)p; p += (size_t)D * D * 2;
    int* esrc = (int*)p;             p += (size_t)N_EDGES * 4;
    int* cstart = (int*)p;           p += ((N_NODES + 1) * 4 + 15) / 16 * 16;
    int* cfill = (int*)p;            p += (size_t)N_NODES * 4;
    int* psum = (int*)p;             p += ((NBLK_SCAN + 3) / 4) * 16;
    int* gstart = (int*)p;           p += 256;

    // scalar-path scratch lives in hB (free after L3 writes hA)
    float* vbeta = hB;
    float* s_arr = hB + 256;
    float* a_arr = hB + 256 + N_NODES;

    // ---- CSR build ----
    hipMemsetAsync(cfill, 0, (size_t)N_NODES * 4, stream);
    count_deg_k<<<(N_EDGES + 255) / 256, 256, 0, stream>>>(col, cfill);
    partial_k<<<NBLK_SCAN, 256, 0, stream>>>(cfill, psum);
    scanpart_k<<<1, 512, 0, stream>>>(psum);
    scan_scatter_k<<<NBLK_SCAN, 256, 0, stream>>>(cfill, psum, cstart);
    hipMemsetAsync(cfill, 0, (size_t)N_NODES * 4, stream);
    fill_csr_k<<<(N_EDGES + 255) / 256, 256, 0, stream>>>(row, col, cstart, cfill, esrc);

    // ---- graph bounds ----
    bounds_k<<<1, 128, 0, stream>>>(batch, gstart);

    const int fgrid = (N_NODES + FTILE - 1) / FTILE;  // 1563
    const int wn4 = D * D / 4;                        // 4096

    // ---- Fused layers 1-3 (aggregate-then-transform, exact by linearity) ----
    split_k<<<(wn4 + 255) / 256, 256, 0, stream>>>(W1, whi, wlo, wn4);
    fused_layer_k<<<fgrid, 256, 0, stream>>>(x, whi, wlo, b1, cstart, esrc, hA);
    split_k<<<(wn4 + 255) / 256, 256, 0, stream>>>(W2, whi, wlo, wn4);
    fused_layer_k<<<fgrid, 256, 0, stream>>>(hA, whi, wlo, b2, cstart, esrc, hB);
    split_k<<<(wn4 + 255) / 256, 256, 0, stream>>>(W3, whi, wlo, wn4);
    fused_layer_k<<<fgrid, 256, 0, stream>>>(hB, whi, wlo, b3, cstart, esrc, hA);

    // ---- Collapsed layer 4 + pool + head (reads hA = h3; scratch in hB) ----
    vbeta_k<<<1, 128, 0, stream>>>(W4, b4, Wc, vbeta);
    matvec_k<<<N_NODES / 4, 256, 0, stream>>>(hA, vbeta, s_arr);
    sagg_k<<<(N_NODES + 255) / 256, 256, 0, stream>>>(s_arr, cstart, esrc, vbeta, a_arr);
    spool_k<<<N_GRAPHS, 256, 0, stream>>>(a_arr, gstart, bc, out);
}

// Round 17
// 455.064 us; speedup vs baseline: 1.0600x; 1.0600x over previous
//
#include <hip/hip_runtime.h>
#include <hip/hip_bf16.h>

#define N_NODES 100000
#define N_EDGES 600000
#define N_GRAPHS 64
#define D 128

#define NBLK_SCAN ((N_NODES + 255) / 256)  // 391

typedef __attribute__((ext_vector_type(8))) short short8v;
typedef __attribute__((ext_vector_type(4))) float float4v;

__device__ __forceinline__ unsigned short f2bf(float f) {
    unsigned int u = __float_as_uint(f);
    return (unsigned short)((u + 0x7FFF + ((u >> 16) & 1)) >> 16);  // RNE
}
__device__ __forceinline__ float bf2f(unsigned short h) {
    return __uint_as_float(((unsigned int)h) << 16);
}

// ---------------- CSR build ----------------

__global__ void count_deg_k(const int* __restrict__ col, int* __restrict__ cnt) {
    int e = blockIdx.x * blockDim.x + threadIdx.x;
    if (e < N_EDGES) atomicAdd(&cnt[col[e]], 1);
}

__global__ __launch_bounds__(256) void partial_k(const int* __restrict__ cnt,
                                                 int* __restrict__ psum) {
    int i = blockIdx.x * 256 + threadIdx.x;
    int v = (i < N_NODES) ? cnt[i] : 0;
#pragma unroll
    for (int d = 32; d > 0; d >>= 1) v += __shfl_down(v, d, 64);
    __shared__ int ws[4];
    if ((threadIdx.x & 63) == 0) ws[threadIdx.x >> 6] = v;
    __syncthreads();
    if (threadIdx.x == 0) psum[blockIdx.x] = ws[0] + ws[1] + ws[2] + ws[3];
}

__global__ __launch_bounds__(512) void scanpart_k(int* __restrict__ psum) {
    __shared__ int ls[512];
    int t = threadIdx.x;
    int v = (t < NBLK_SCAN) ? psum[t] : 0;
    ls[t] = v;
    __syncthreads();
    for (int d = 1; d < 512; d <<= 1) {
        int u = (t >= d) ? ls[t - d] : 0;
        __syncthreads();
        ls[t] += u;
        __syncthreads();
    }
    if (t < NBLK_SCAN) psum[t] = ls[t] - v;  // exclusive
}

__global__ __launch_bounds__(256) void scan_scatter_k(const int* __restrict__ cnt,
                                                      const int* __restrict__ psum,
                                                      int* __restrict__ start) {
    int b = blockIdx.x, t = threadIdx.x;
    int i = b * 256 + t;
    int v = (i < N_NODES) ? cnt[i] : 0;
    __shared__ int ls[256];
    ls[t] = v;
    __syncthreads();
    for (int d = 1; d < 256; d <<= 1) {
        int u = (t >= d) ? ls[t - d] : 0;
        __syncthreads();
        ls[t] += u;
        __syncthreads();
    }
    int incl = ls[t];
    int off = psum[b];
    if (i < N_NODES) start[i] = off + incl - v;
    if (i == N_NODES - 1) start[N_NODES] = off + incl;
}

__global__ void fill_csr_k(const int* __restrict__ row, const int* __restrict__ col,
                           const int* __restrict__ start, int* __restrict__ fill,
                           int* __restrict__ esrc) {
    int e = blockIdx.x * blockDim.x + threadIdx.x;
    if (e < N_EDGES) {
        int c = col[e];
        int p = atomicAdd(&fill[c], 1);
        esrc[start[c] + p] = row[e];
    }
}

// ---------------- graph segment bounds (batch is sorted) ----------------

__global__ __launch_bounds__(128) void bounds_k(const int* __restrict__ batch,
                                                int* __restrict__ gstart) {
    int g = threadIdx.x;
    if (g > N_GRAPHS) return;
    int lo = 0, hi = N_NODES;
    while (lo < hi) {
        int mid = (lo + hi) >> 1;
        if (batch[mid] < g) lo = mid + 1; else hi = mid;
    }
    gstart[g] = lo;
}

// ---------------- f32 -> (bf16 hi, bf16 lo) split (weights only) ----------------

__global__ __launch_bounds__(256) void split_k(const float* __restrict__ in,
                                               unsigned short* __restrict__ hi,
                                               unsigned short* __restrict__ lo, int n4) {
    int i = blockIdx.x * 256 + threadIdx.x;
    if (i >= n4) return;
    float4 v = reinterpret_cast<const float4*>(in)[i];
    ushort4 h, l;
    h.x = f2bf(v.x); l.x = f2bf(v.x - bf2f(h.x));
    h.y = f2bf(v.y); l.y = f2bf(v.y - bf2f(h.y));
    h.z = f2bf(v.z); l.z = f2bf(v.z - bf2f(h.z));
    h.w = f2bf(v.w); l.w = f2bf(v.w - bf2f(h.w));
    reinterpret_cast<ushort4*>(hi)[i] = h;
    reinterpret_cast<ushort4*>(lo)[i] = l;
}

// ---------------- Fused layer: hout = relu(W * (h_i + sum_src h_src) + (1+deg)*b)
// h stays f32 end-to-end. Per block (128 thr): 32 output rows. R16 lesson:
// 64-row/256-thr version had 34KB LDS -> 33% occupancy -> gather at half rate.
// 32-row/128-thr halves LDS to ~17KB -> ~9 blocks/CU (~56% occ).
// Phase 1: half-wave-per-row f32 gather (contiguous 512B/row requests) + 4-edge
//   ILP -> f32 LDS tile.  Phase 2: per-wave 16 rows, in-register hi/lo bf16
//   split, W hi/lo direct from L2, 4-term split-bf16 MFMA, de-scatter through
//   wave-private LDS slice, 512B row stores.

#define FTILE 32
#define FPITCH 132  // f32 words; 16B-aligned rows, stride-132 -> 2-way banks

__global__ __launch_bounds__(128) void fused_layer_k(
    const float* __restrict__ hin,
    const unsigned short* __restrict__ Whi, const unsigned short* __restrict__ Wlo,
    const float* __restrict__ bias,
    const int* __restrict__ start, const int* __restrict__ esrc,
    float* __restrict__ hout) {
    __shared__ float tile[FTILE * FPITCH];  // 16.9KB
    __shared__ float scnt[FTILE];
    const int tid = threadIdx.x;
    const int n0 = blockIdx.x * FTILE;

    // ---- phase 1: gather-aggregate ----
    {
        const int hw = tid >> 5, li = tid & 31;  // 4 half-waves
        for (int it = 0; it < 8; ++it) {
            const int r = it * 4 + hw;
            const int node = n0 + r;
            float4 acc = make_float4(0.f, 0.f, 0.f, 0.f);
            int deg = 0;
            if (node < N_NODES) {
                const int s = start[node], e = start[node + 1];
                deg = e - s;
                acc = *reinterpret_cast<const float4*>(hin + ((size_t)node << 7) + 4 * li);
                int i = s;
                for (; i + 3 < e; i += 4) {
                    const float4 v0 = *reinterpret_cast<const float4*>(hin + (((size_t)esrc[i] << 7) + 4 * li));
                    const float4 v1 = *reinterpret_cast<const float4*>(hin + (((size_t)esrc[i + 1] << 7) + 4 * li));
                    const float4 v2 = *reinterpret_cast<const float4*>(hin + (((size_t)esrc[i + 2] << 7) + 4 * li));
                    const float4 v3 = *reinterpret_cast<const float4*>(hin + (((size_t)esrc[i + 3] << 7) + 4 * li));
                    acc.x += (v0.x + v1.x) + (v2.x + v3.x);
                    acc.y += (v0.y + v1.y) + (v2.y + v3.y);
                    acc.z += (v0.z + v1.z) + (v2.z + v3.z);
                    acc.w += (v0.w + v1.w) + (v2.w + v3.w);
                }
                for (; i < e; ++i) {
                    const float4 v = *reinterpret_cast<const float4*>(hin + (((size_t)esrc[i] << 7) + 4 * li));
                    acc.x += v.x; acc.y += v.y; acc.z += v.z; acc.w += v.w;
                }
            }
            *reinterpret_cast<float4*>(&tile[r * FPITCH + 4 * li]) = acc;
            if (li == 0) scnt[r] = (float)(1 + deg);
        }
    }
    __syncthreads();

    // ---- phase 2: per-wave 16 rows x 128 cols split-bf16 MFMA ----
    const int l = tid & 63, wv = tid >> 6;  // 2 waves
    const int g = l >> 4, li16 = l & 15;

    float4v acc[8];
#pragma unroll
    for (int cg = 0; cg < 8; ++cg) acc[cg] = (float4v){0.f, 0.f, 0.f, 0.f};

#pragma unroll
    for (int kk = 0; kk < 4; ++kk) {
        const int k0 = kk * 32;
        const float* tp = &tile[(wv * 16 + li16) * FPITCH + k0 + g * 8];
        float4 f0 = *reinterpret_cast<const float4*>(tp);
        float4 f1 = *reinterpret_cast<const float4*>(tp + 4);
        float fv[8] = {f0.x, f0.y, f0.z, f0.w, f1.x, f1.y, f1.z, f1.w};
        short8v ah, al;
#pragma unroll
        for (int j = 0; j < 8; ++j) {
            unsigned short h = f2bf(fv[j]);
            ah[j] = (short)h;
            al[j] = (short)f2bf(fv[j] - bf2f(h));
        }
#pragma unroll
        for (int cg = 0; cg < 8; ++cg) {
            const size_t wb = (size_t)(cg * 16 + li16) * D + g * 8 + k0;
            short8v wh = *reinterpret_cast<const short8v*>(Whi + wb);
            short8v wl = *reinterpret_cast<const short8v*>(Wlo + wb);
            acc[cg] = __builtin_amdgcn_mfma_f32_16x16x32_bf16(ah, wh, acc[cg], 0, 0, 0);
            acc[cg] = __builtin_amdgcn_mfma_f32_16x16x32_bf16(al, wh, acc[cg], 0, 0, 0);
            acc[cg] = __builtin_amdgcn_mfma_f32_16x16x32_bf16(ah, wl, acc[cg], 0, 0, 0);
            acc[cg] = __builtin_amdgcn_mfma_f32_16x16x32_bf16(al, wl, acc[cg], 0, 0, 0);
        }
    }

    // de-scatter C/D (row=g*4+r, col=cg*16+li16) into own tile slice
    // (wave-private rows; per-wave DS ordering makes this barrier-free)
#pragma unroll
    for (int cg = 0; cg < 8; ++cg)
#pragma unroll
        for (int r = 0; r < 4; ++r)
            tile[(wv * 16 + g * 4 + r) * FPITCH + cg * 16 + li16] = acc[cg][r];

    // epilogue: rows contiguous, +cnt*bias, relu, 512B row stores
    const int c4 = l & 31, rh = l >> 5;
    const float4 bv = *reinterpret_cast<const float4*>(&bias[4 * c4]);
#pragma unroll
    for (int it = 0; it < 8; ++it) {
        const int rowl = wv * 16 + it * 2 + rh;
        const int grow = n0 + rowl;
        if (grow < N_NODES) {
            float4 v = *reinterpret_cast<const float4*>(&tile[rowl * FPITCH + 4 * c4]);
            const float c = scnt[rowl];
            v.x = fmaxf(fmaf(c, bv.x, v.x), 0.f);
            v.y = fmaxf(fmaf(c, bv.y, v.y), 0.f);
            v.z = fmaxf(fmaf(c, bv.z, v.z), 0.f);
            v.w = fmaxf(fmaf(c, bv.w, v.w), 0.f);
            *reinterpret_cast<float4*>(&hout[(size_t)grow * D + 4 * c4]) = v;
        }
    }
}

// ---------------- Collapsed layer 4 + pool + head ----------------
// logit_g = (1/c_g) * sum_{i in g} [ s[i] + sum_{src->i} s[src] + (1+deg_i)*beta ] + bc
// where s[i] = h3[i] . v,  v = Wc @ W4,  beta = Wc . b4.

__global__ __launch_bounds__(128) void vbeta_k(const float* __restrict__ W4,
                                               const float* __restrict__ b4,
                                               const float* __restrict__ Wc,
                                               float* __restrict__ vbeta) {
    int k = threadIdx.x;
    float acc = 0.f;
    for (int j = 0; j < D; ++j) acc = fmaf(Wc[j], W4[j * D + k], acc);
    vbeta[k] = acc;
    __shared__ float red[128];
    red[k] = Wc[k] * b4[k];
    __syncthreads();
    for (int st = 64; st > 0; st >>= 1) {
        if (k < st) red[k] += red[k + st];
        __syncthreads();
    }
    if (k == 0) vbeta[D] = red[0];
}

__global__ __launch_bounds__(256) void matvec_k(const float* __restrict__ h,
                                                const float* __restrict__ vbeta,
                                                float* __restrict__ s) {
    int wid = threadIdx.x >> 6, lane = threadIdx.x & 63;
    int row = blockIdx.x * 4 + wid;
    const float2 hv = *reinterpret_cast<const float2*>(&h[(size_t)row * D + lane * 2]);
    const float2 vv = *reinterpret_cast<const float2*>(&vbeta[lane * 2]);
    float dot = fmaf(hv.x, vv.x, hv.y * vv.y);
#pragma unroll
    for (int d = 32; d > 0; d >>= 1) dot += __shfl_down(dot, d, 64);
    if (lane == 0) s[row] = dot;
}

__global__ __launch_bounds__(256) void sagg_k(const float* __restrict__ s,
                                              const int* __restrict__ start,
                                              const int* __restrict__ esrc,
                                              const float* __restrict__ vbeta,
                                              float* __restrict__ a) {
    int i = blockIdx.x * 256 + threadIdx.x;
    if (i >= N_NODES) return;
    int s0 = start[i], s1 = start[i + 1];
    float beta = vbeta[D];
    float acc = s[i] + (float)(1 + s1 - s0) * beta;
    for (int e = s0; e < s1; ++e) acc += s[esrc[e]];
    a[i] = acc;
}

__global__ __launch_bounds__(256) void spool_k(const float* __restrict__ a,
                                               const int* __restrict__ gstart,
                                               const float* __restrict__ bc,
                                               float* __restrict__ out) {
    int g = blockIdx.x;
    int lo = gstart[g], hi = gstart[g + 1];
    float acc = 0.f;
    for (int i = lo + threadIdx.x; i < hi; i += 256) acc += a[i];
    __shared__ float red[256];
    red[threadIdx.x] = acc;
    __syncthreads();
    for (int st = 128; st > 0; st >>= 1) {
        if (threadIdx.x < st) red[threadIdx.x] += red[threadIdx.x + st];
        __syncthreads();
    }
    if (threadIdx.x == 0) {
        float c = (float)max(hi - lo, 1);
        out[g] = 1.f / (1.f + expf(-(red[0] / c + bc[0])));
    }
}

// ---------------- Launch ----------------

extern "C" void kernel_launch(void* const* d_in, const int* in_sizes, int n_in,
                              void* d_out, int out_size, void* d_ws, size_t ws_size,
                              hipStream_t stream) {
    const float* x   = (const float*)d_in[0];
    const int* ei    = (const int*)d_in[1];
    const int* batch = (const int*)d_in[2];
    const float* W1  = (const float*)d_in[3];
    const float* b1  = (const float*)d_in[4];
    const float* W2  = (const float*)d_in[5];
    const float* b2  = (const float*)d_in[6];
    const float* W3  = (const float*)d_in[7];
    const float* b3  = (const float*)d_in[8];
    const float* W4  = (const float*)d_in[9];
    const float* b4  = (const float*)d_in[10];
    const float* Wc  = (const float*)d_in[11];
    const float* bc  = (const float*)d_in[12];
    float* out = (float*)d_out;

    const int* row = ei;             // sources
    const int* col = ei + N_EDGES;   // targets

    char* p = (char*)d_ws;
    float* hA = (float*)p;           p += (size_t)N_NODES * D * 4;   // 51.2 MB
    float* hB = (float*)p;           p += (size_t)N_NODES * D * 4;   // 51.2 MB
    unsigned short* whi = (unsigned short*)p; p += (size_t)D * D * 2;
    unsigned short* wlo = (unsigned short*)p; p += (size_t)D * D * 2;
    int* esrc = (int*)p;             p += (size_t)N_EDGES * 4;
    int* cstart = (int*)p;           p += ((N_NODES + 1) * 4 + 15) / 16 * 16;
    int* cfill = (int*)p;            p += (size_t)N_NODES * 4;
    int* psum = (int*)p;             p += ((NBLK_SCAN + 3) / 4) * 16;
    int* gstart = (int*)p;           p += 256;

    // scalar-path scratch lives in hB (free after L3 writes hA)
    float* vbeta = hB;
    float* s_arr = hB + 256;
    float* a_arr = hB + 256 + N_NODES;

    // ---- CSR build ----
    hipMemsetAsync(cfill, 0, (size_t)N_NODES * 4, stream);
    count_deg_k<<<(N_EDGES + 255) / 256, 256, 0, stream>>>(col, cfill);
    partial_k<<<NBLK_SCAN, 256, 0, stream>>>(cfill, psum);
    scanpart_k<<<1, 512, 0, stream>>>(psum);
    scan_scatter_k<<<NBLK_SCAN, 256, 0, stream>>>(cfill, psum, cstart);
    hipMemsetAsync(cfill, 0, (size_t)N_NODES * 4, stream);
    fill_csr_k<<<(N_EDGES + 255) / 256, 256, 0, stream>>>(row, col, cstart, cfill, esrc);

    // ---- graph bounds ----
    bounds_k<<<1, 128, 0, stream>>>(batch, gstart);

    const int fgrid = (N_NODES + FTILE - 1) / FTILE;  // 3125
    const int wn4 = D * D / 4;                        // 4096

    // ---- Fused layers 1-3 (aggregate-then-transform, exact by linearity) ----
    split_k<<<(wn4 + 255) / 256, 256, 0, stream>>>(W1, whi, wlo, wn4);
    fused_layer_k<<<fgrid, 128, 0, stream>>>(x, whi, wlo, b1, cstart, esrc, hA);
    split_k<<<(wn4 + 255) / 256, 256, 0, stream>>>(W2, whi, wlo, wn4);
    fused_layer_k<<<fgrid, 128, 0, stream>>>(hA, whi, wlo, b2, cstart, esrc, hB);
    split_k<<<(wn4 + 255) / 256, 256, 0, stream>>>(W3, whi, wlo, wn4);
    fused_layer_k<<<fgrid, 128, 0, stream>>>(hB, whi, wlo, b3, cstart, esrc, hA);

    // ---- Collapsed layer 4 + pool + head (reads hA = h3; scratch in hB) ----
    vbeta_k<<<1, 128, 0, stream>>>(W4, b4, Wc, vbeta);
    matvec_k<<<N_NODES / 4, 256, 0, stream>>>(hA, vbeta, s_arr);
    sagg_k<<<(N_NODES + 255) / 256, 256, 0, stream>>>(s_arr, cstart, esrc, vbeta, a_arr);
    spool_k<<<N_GRAPHS, 256, 0, stream>>>(a_arr, gstart, bc, out);
}

// Round 18
// 414.949 us; speedup vs baseline: 1.1624x; 1.0967x over previous
//
#include <hip/hip_runtime.h>
#include <hip/hip_bf16.h>

#define N_NODES 100000
#define N_EDGES 600000
#define N_GRAPHS 64
#define D 128

#define NBLK_SCAN ((N_NODES + 255) / 256)  // 391

typedef __attribute__((ext_vector_type(8))) short short8v;
typedef __attribute__((ext_vector_type(4))) float float4v;

__device__ __forceinline__ unsigned short f2bf(float f) {
    unsigned int u = __float_as_uint(f);
    return (unsigned short)((u + 0x7FFF + ((u >> 16) & 1)) >> 16);  // RNE
}
__device__ __forceinline__ float bf2f(unsigned short h) {
    return __uint_as_float(((unsigned int)h) << 16);
}

// ---------------- CSR build ----------------

__global__ void count_deg_k(const int* __restrict__ col, int* __restrict__ cnt) {
    int e = blockIdx.x * blockDim.x + threadIdx.x;
    if (e < N_EDGES) atomicAdd(&cnt[col[e]], 1);
}

__global__ __launch_bounds__(256) void partial_k(const int* __restrict__ cnt,
                                                 int* __restrict__ psum) {
    int i = blockIdx.x * 256 + threadIdx.x;
    int v = (i < N_NODES) ? cnt[i] : 0;
#pragma unroll
    for (int d = 32; d > 0; d >>= 1) v += __shfl_down(v, d, 64);
    __shared__ int ws[4];
    if ((threadIdx.x & 63) == 0) ws[threadIdx.x >> 6] = v;
    __syncthreads();
    if (threadIdx.x == 0) psum[blockIdx.x] = ws[0] + ws[1] + ws[2] + ws[3];
}

__global__ __launch_bounds__(512) void scanpart_k(int* __restrict__ psum) {
    __shared__ int ls[512];
    int t = threadIdx.x;
    int v = (t < NBLK_SCAN) ? psum[t] : 0;
    ls[t] = v;
    __syncthreads();
    for (int d = 1; d < 512; d <<= 1) {
        int u = (t >= d) ? ls[t - d] : 0;
        __syncthreads();
        ls[t] += u;
        __syncthreads();
    }
    if (t < NBLK_SCAN) psum[t] = ls[t] - v;  // exclusive
}

__global__ __launch_bounds__(256) void scan_scatter_k(const int* __restrict__ cnt,
                                                      const int* __restrict__ psum,
                                                      int* __restrict__ start) {
    int b = blockIdx.x, t = threadIdx.x;
    int i = b * 256 + t;
    int v = (i < N_NODES) ? cnt[i] : 0;
    __shared__ int ls[256];
    ls[t] = v;
    __syncthreads();
    for (int d = 1; d < 256; d <<= 1) {
        int u = (t >= d) ? ls[t - d] : 0;
        __syncthreads();
        ls[t] += u;
        __syncthreads();
    }
    int incl = ls[t];
    int off = psum[b];
    if (i < N_NODES) start[i] = off + incl - v;
    if (i == N_NODES - 1) start[N_NODES] = off + incl;
}

__global__ void fill_csr_k(const int* __restrict__ row, const int* __restrict__ col,
                           const int* __restrict__ start, int* __restrict__ fill,
                           int* __restrict__ esrc) {
    int e = blockIdx.x * blockDim.x + threadIdx.x;
    if (e < N_EDGES) {
        int c = col[e];
        int p = atomicAdd(&fill[c], 1);
        esrc[start[c] + p] = row[e];
    }
}

// ---------------- graph segment bounds (batch is sorted) ----------------

__global__ __launch_bounds__(128) void bounds_k(const int* __restrict__ batch,
                                                int* __restrict__ gstart) {
    int g = threadIdx.x;
    if (g > N_GRAPHS) return;
    int lo = 0, hi = N_NODES;
    while (lo < hi) {
        int mid = (lo + hi) >> 1;
        if (batch[mid] < g) lo = mid + 1; else hi = mid;
    }
    gstart[g] = lo;
}

// ---------------- f32 -> (bf16 hi, bf16 lo) split (weights only) ----------------

__global__ __launch_bounds__(256) void split_k(const float* __restrict__ in,
                                               unsigned short* __restrict__ hi,
                                               unsigned short* __restrict__ lo, int n4) {
    int i = blockIdx.x * 256 + threadIdx.x;
    if (i >= n4) return;
    float4 v = reinterpret_cast<const float4*>(in)[i];
    ushort4 h, l;
    h.x = f2bf(v.x); l.x = f2bf(v.x - bf2f(h.x));
    h.y = f2bf(v.y); l.y = f2bf(v.y - bf2f(h.y));
    h.z = f2bf(v.z); l.z = f2bf(v.z - bf2f(h.z));
    h.w = f2bf(v.w); l.w = f2bf(v.w - bf2f(h.w));
    reinterpret_cast<ushort4*>(hi)[i] = h;
    reinterpret_cast<ushort4*>(lo)[i] = l;
}

// ---------------- Split-bf16 MFMA GEMM (R15 measured-good) ----------------
// out[i][j] = bias[j] + sum_k (Ahi+Alo)[i][k]*(Whi+Wlo)[j][k]  (4 mfma terms,
// f32 accumulate). mfma_f32_16x16x32_bf16: A/B frag = 8 bf16/lane, non-k dim =
// lane&15, k = (lane>>4)*8 + j (same packing both operands -> internal k-perm
// cancels). C/D: row=(lane>>4)*4+reg, col=lane&15 (m89/m91-verified).
// Operands load DIRECT from global (A rows read once; W 64KB L2-hot).
// No barriers: epilogue de-scatters acc through per-wave-private LDS.

#define BM 128

__global__ __launch_bounds__(256) void gemm_mfma_k(
    const unsigned short* __restrict__ Ahi, const unsigned short* __restrict__ Alo,
    const unsigned short* __restrict__ Whi, const unsigned short* __restrict__ Wlo,
    const float* __restrict__ bias, float* __restrict__ out, int nrows) {
    __shared__ float swp[4][32][132];  // per-wave-private slices
    const int tid = threadIdx.x, l = tid & 63, wv = tid >> 6;
    const int bm0 = blockIdx.x * BM;
    const int g = l >> 4, li = l & 15;

    float4v acc[2][8];
#pragma unroll
    for (int rg = 0; rg < 2; ++rg)
#pragma unroll
        for (int cg = 0; cg < 8; ++cg) acc[rg][cg] = (float4v){0.f, 0.f, 0.f, 0.f};

    size_t abase[2];
#pragma unroll
    for (int rg = 0; rg < 2; ++rg)
        abase[rg] = (size_t)min(bm0 + wv * 32 + rg * 16 + li, nrows - 1) * D + g * 8;

#pragma unroll
    for (int kk = 0; kk < 4; ++kk) {
        const int k0 = kk * 32;
        short8v ah[2], al[2];
#pragma unroll
        for (int rg = 0; rg < 2; ++rg) {
            ah[rg] = *reinterpret_cast<const short8v*>(Ahi + abase[rg] + k0);
            al[rg] = *reinterpret_cast<const short8v*>(Alo + abase[rg] + k0);
        }
#pragma unroll
        for (int cg = 0; cg < 8; ++cg) {
            const size_t wb = (size_t)(cg * 16 + li) * D + g * 8 + k0;
            short8v wh = *reinterpret_cast<const short8v*>(Whi + wb);
            short8v wl = *reinterpret_cast<const short8v*>(Wlo + wb);
#pragma unroll
            for (int rg = 0; rg < 2; ++rg) {
                acc[rg][cg] = __builtin_amdgcn_mfma_f32_16x16x32_bf16(ah[rg], wh, acc[rg][cg], 0, 0, 0);
                acc[rg][cg] = __builtin_amdgcn_mfma_f32_16x16x32_bf16(al[rg], wh, acc[rg][cg], 0, 0, 0);
                acc[rg][cg] = __builtin_amdgcn_mfma_f32_16x16x32_bf16(ah[rg], wl, acc[rg][cg], 0, 0, 0);
                acc[rg][cg] = __builtin_amdgcn_mfma_f32_16x16x32_bf16(al[rg], wl, acc[rg][cg], 0, 0, 0);
            }
        }
    }

#pragma unroll
    for (int rg = 0; rg < 2; ++rg)
#pragma unroll
        for (int cg = 0; cg < 8; ++cg)
#pragma unroll
            for (int r = 0; r < 4; ++r)
                swp[wv][rg * 16 + g * 4 + r][cg * 16 + li] = acc[rg][cg][r];

    const int c4 = l & 31, rh = l >> 5;
    const float4 bias_v = *reinterpret_cast<const float4*>(&bias[c4 * 4]);
#pragma unroll
    for (int it = 0; it < 16; ++it) {
        int rowl = it * 2 + rh;
        int grow = bm0 + wv * 32 + rowl;
        if (grow < nrows) {
            float4 v = *reinterpret_cast<const float4*>(&swp[wv][rowl][c4 * 4]);
            v.x += bias_v.x; v.y += bias_v.y; v.z += bias_v.z; v.w += bias_v.w;
            *reinterpret_cast<float4*>(&out[(size_t)grow * D + c4 * 4]) = v;
        }
    }
}

// Layer-1 variant: A is f32 (x); split to bf16 hi/lo in registers.
__global__ __launch_bounds__(256) void gemm_mfma_f32_k(
    const float* __restrict__ A,
    const unsigned short* __restrict__ Whi, const unsigned short* __restrict__ Wlo,
    const float* __restrict__ bias, float* __restrict__ out, int nrows) {
    __shared__ float swp[4][32][132];
    const int tid = threadIdx.x, l = tid & 63, wv = tid >> 6;
    const int bm0 = blockIdx.x * BM;
    const int g = l >> 4, li = l & 15;

    float4v acc[2][8];
#pragma unroll
    for (int rg = 0; rg < 2; ++rg)
#pragma unroll
        for (int cg = 0; cg < 8; ++cg) acc[rg][cg] = (float4v){0.f, 0.f, 0.f, 0.f};

    size_t abase[2];
#pragma unroll
    for (int rg = 0; rg < 2; ++rg)
        abase[rg] = (size_t)min(bm0 + wv * 32 + rg * 16 + li, nrows - 1) * D + g * 8;

#pragma unroll
    for (int kk = 0; kk < 4; ++kk) {
        const int k0 = kk * 32;
        short8v ah[2], al[2];
#pragma unroll
        for (int rg = 0; rg < 2; ++rg) {
            float4 f0 = *reinterpret_cast<const float4*>(A + abase[rg] + k0);
            float4 f1 = *reinterpret_cast<const float4*>(A + abase[rg] + k0 + 4);
            float fv[8] = {f0.x, f0.y, f0.z, f0.w, f1.x, f1.y, f1.z, f1.w};
#pragma unroll
            for (int j = 0; j < 8; ++j) {
                unsigned short h = f2bf(fv[j]);
                ah[rg][j] = (short)h;
                al[rg][j] = (short)f2bf(fv[j] - bf2f(h));
            }
        }
#pragma unroll
        for (int cg = 0; cg < 8; ++cg) {
            const size_t wb = (size_t)(cg * 16 + li) * D + g * 8 + k0;
            short8v wh = *reinterpret_cast<const short8v*>(Whi + wb);
            short8v wl = *reinterpret_cast<const short8v*>(Wlo + wb);
#pragma unroll
            for (int rg = 0; rg < 2; ++rg) {
                acc[rg][cg] = __builtin_amdgcn_mfma_f32_16x16x32_bf16(ah[rg], wh, acc[rg][cg], 0, 0, 0);
                acc[rg][cg] = __builtin_amdgcn_mfma_f32_16x16x32_bf16(al[rg], wh, acc[rg][cg], 0, 0, 0);
                acc[rg][cg] = __builtin_amdgcn_mfma_f32_16x16x32_bf16(ah[rg], wl, acc[rg][cg], 0, 0, 0);
                acc[rg][cg] = __builtin_amdgcn_mfma_f32_16x16x32_bf16(al[rg], wl, acc[rg][cg], 0, 0, 0);
            }
        }
    }

#pragma unroll
    for (int rg = 0; rg < 2; ++rg)
#pragma unroll
        for (int cg = 0; cg < 8; ++cg)
#pragma unroll
            for (int r = 0; r < 4; ++r)
                swp[wv][rg * 16 + g * 4 + r][cg * 16 + li] = acc[rg][cg][r];

    const int c4 = l & 31, rh = l >> 5;
    const float4 bias_v = *reinterpret_cast<const float4*>(&bias[c4 * 4]);
#pragma unroll
    for (int it = 0; it < 16; ++it) {
        int rowl = it * 2 + rh;
        int grow = bm0 + wv * 32 + rowl;
        if (grow < nrows) {
            float4 v = *reinterpret_cast<const float4*>(&swp[wv][rowl][c4 * 4]);
            v.x += bias_v.x; v.y += bias_v.y; v.z += bias_v.z; v.w += bias_v.w;
            *reinterpret_cast<float4*>(&out[(size_t)grow * D + c4 * 4]) = v;
        }
    }
}

// ---------------- Aggregation: (t f32 gather) -> bf16 hi/lo pair ----------------
// Half-wave per node, float4 per lane (one 512B request/row). Branchless
// 8-deep gather: idx = in-range ? esrc[..] : N_NODES (dedicated ZERO row),
// 8 unconditional loads in static registers -> E[rounds] drops 1.8 -> 1.16
// (round-latency model: R15's VGPR=20 showed only ~4 loads in flight).

__global__ __launch_bounds__(256) void aggregate_k(const float* __restrict__ t,
                                                   const int* __restrict__ start,
                                                   const int* __restrict__ esrc,
                                                   unsigned short* __restrict__ ohi,
                                                   unsigned short* __restrict__ olo,
                                                   int do_relu) {
    const int wv = threadIdx.x >> 6, l = threadIdx.x & 63;
    const int half = l >> 5, li = l & 31;
    const int node = blockIdx.x * 8 + wv * 2 + half;
    if (node >= N_NODES) return;
    const int s = start[node], e = start[node + 1];
    const size_t base = ((size_t)node << 7) + 4 * li;
    float4 acc = *reinterpret_cast<const float4*>(t + base);  // self loop
    for (int i = s; i < e; i += 8) {
        int idx[8];
#pragma unroll
        for (int j = 0; j < 8; ++j)
            idx[j] = (i + j < e) ? esrc[i + j] : N_NODES;  // sentinel = zero row
        float4 v[8];
#pragma unroll
        for (int j = 0; j < 8; ++j)
            v[j] = *reinterpret_cast<const float4*>(t + (((size_t)idx[j] << 7) + 4 * li));
        acc.x += ((v[0].x + v[1].x) + (v[2].x + v[3].x)) + ((v[4].x + v[5].x) + (v[6].x + v[7].x));
        acc.y += ((v[0].y + v[1].y) + (v[2].y + v[3].y)) + ((v[4].y + v[5].y) + (v[6].y + v[7].y));
        acc.z += ((v[0].z + v[1].z) + (v[2].z + v[3].z)) + ((v[4].z + v[5].z) + (v[6].z + v[7].z));
        acc.w += ((v[0].w + v[1].w) + (v[2].w + v[3].w)) + ((v[4].w + v[5].w) + (v[6].w + v[7].w));
    }
    if (do_relu) {
        acc.x = fmaxf(acc.x, 0.f);
        acc.y = fmaxf(acc.y, 0.f);
        acc.z = fmaxf(acc.z, 0.f);
        acc.w = fmaxf(acc.w, 0.f);
    }
    ushort4 h, lo4;
    h.x = f2bf(acc.x); lo4.x = f2bf(acc.x - bf2f(h.x));
    h.y = f2bf(acc.y); lo4.y = f2bf(acc.y - bf2f(h.y));
    h.z = f2bf(acc.z); lo4.z = f2bf(acc.z - bf2f(h.z));
    h.w = f2bf(acc.w); lo4.w = f2bf(acc.w - bf2f(h.w));
    *reinterpret_cast<ushort4*>(ohi + base) = h;
    *reinterpret_cast<ushort4*>(olo + base) = lo4;
}

// ---------------- Collapsed layer 4 + pool + head ----------------
// logit_g = (1/c_g) * sum_{i in g} [ s[i] + sum_{src->i} s[src] + (1+deg_i)*beta ] + bc
// where s[i] = h3[i] . v,  v = Wc @ W4,  beta = Wc . b4.

__global__ __launch_bounds__(128) void vbeta_k(const float* __restrict__ W4,
                                               const float* __restrict__ b4,
                                               const float* __restrict__ Wc,
                                               float* __restrict__ vbeta) {
    int k = threadIdx.x;
    float acc = 0.f;
    for (int j = 0; j < D; ++j) acc = fmaf(Wc[j], W4[j * D + k], acc);
    vbeta[k] = acc;
    __shared__ float red[128];
    red[k] = Wc[k] * b4[k];
    __syncthreads();
    for (int st = 64; st > 0; st >>= 1) {
        if (k < st) red[k] += red[k + st];
        __syncthreads();
    }
    if (k == 0) vbeta[D] = red[0];
}

__global__ __launch_bounds__(256) void matvec_k(const unsigned short* __restrict__ hhi,
                                                const unsigned short* __restrict__ hlo,
                                                const float* __restrict__ vbeta,
                                                float* __restrict__ s) {
    int wid = threadIdx.x >> 6, lane = threadIdx.x & 63;
    int row = blockIdx.x * 4 + wid;
    const size_t base = (size_t)row * D + lane * 2;
    unsigned int h2 = *reinterpret_cast<const unsigned int*>(hhi + base);
    unsigned int l2 = *reinterpret_cast<const unsigned int*>(hlo + base);
    float hx = bf2f((unsigned short)h2) + bf2f((unsigned short)l2);
    float hy = bf2f((unsigned short)(h2 >> 16)) + bf2f((unsigned short)(l2 >> 16));
    const float2 vv = *reinterpret_cast<const float2*>(&vbeta[lane * 2]);
    float dot = fmaf(hx, vv.x, hy * vv.y);
#pragma unroll
    for (int d = 32; d > 0; d >>= 1) dot += __shfl_down(dot, d, 64);
    if (lane == 0) s[row] = dot;
}

__global__ __launch_bounds__(256) void sagg_k(const float* __restrict__ s,
                                              const int* __restrict__ start,
                                              const int* __restrict__ esrc,
                                              const float* __restrict__ vbeta,
                                              float* __restrict__ a) {
    int i = blockIdx.x * 256 + threadIdx.x;
    if (i >= N_NODES) return;
    int s0 = start[i], s1 = start[i + 1];
    float beta = vbeta[D];
    float acc = s[i] + (float)(1 + s1 - s0) * beta;
    for (int e = s0; e < s1; ++e) acc += s[esrc[e]];
    a[i] = acc;
}

__global__ __launch_bounds__(256) void spool_k(const float* __restrict__ a,
                                               const int* __restrict__ gstart,
                                               const float* __restrict__ bc,
                                               float* __restrict__ out) {
    int g = blockIdx.x;
    int lo = gstart[g], hi = gstart[g + 1];
    float acc = 0.f;
    for (int i = lo + threadIdx.x; i < hi; i += 256) acc += a[i];
    __shared__ float red[256];
    red[threadIdx.x] = acc;
    __syncthreads();
    for (int st = 128; st > 0; st >>= 1) {
        if (threadIdx.x < st) red[threadIdx.x] += red[threadIdx.x + st];
        __syncthreads();
    }
    if (threadIdx.x == 0) {
        float c = (float)max(hi - lo, 1);
        out[g] = 1.f / (1.f + expf(-(red[0] / c + bc[0])));
    }
}

// ---------------- Launch ----------------

extern "C" void kernel_launch(void* const* d_in, const int* in_sizes, int n_in,
                              void* d_out, int out_size, void* d_ws, size_t ws_size,
                              hipStream_t stream) {
    const float* x   = (const float*)d_in[0];
    const int* ei    = (const int*)d_in[1];
    const int* batch = (const int*)d_in[2];
    const float* W1  = (const float*)d_in[3];
    const float* b1  = (const float*)d_in[4];
    const float* W2  = (const float*)d_in[5];
    const float* b2  = (const float*)d_in[6];
    const float* W3  = (const float*)d_in[7];
    const float* b3  = (const float*)d_in[8];
    const float* W4  = (const float*)d_in[9];
    const float* b4  = (const float*)d_in[10];
    const float* Wc  = (const float*)d_in[11];
    const float* bc  = (const float*)d_in[12];
    float* out = (float*)d_out;

    const int* row = ei;             // sources
    const int* col = ei + N_EDGES;   // targets

    char* p = (char*)d_ws;
    float* t = (float*)p;            p += (size_t)(N_NODES + 1) * D * 4;  // +1 zero row
    unsigned short* hhi = (unsigned short*)p; p += (size_t)N_NODES * D * 2;
    unsigned short* hlo = (unsigned short*)p; p += (size_t)N_NODES * D * 2;
    unsigned short* whi = (unsigned short*)p; p += (size_t)D * D * 2;
    unsigned short* wlo = (unsigned short*)p; p += (size_t)D * D * 2;
    int* esrc = (int*)p;             p += (size_t)(N_EDGES + 16) * 4;     // +slack for 8-deep over-read
    int* cstart = (int*)p;           p += ((N_NODES + 1) * 4 + 15) / 16 * 16;
    int* cfill = (int*)p;            p += (size_t)N_NODES * 4;
    int* psum = (int*)p;             p += ((NBLK_SCAN + 3) / 4) * 16;
    int* gstart = (int*)p;           p += 256;

    // scalar-path scratch lives in t rows 0.. (free after layer-3 aggregate);
    // zero row N_NODES is far above this region.
    float* vbeta = t;
    float* s_arr = t + 256;
    float* a_arr = t + 256 + N_NODES;

    // ---- zero the gather sentinel row ----
    hipMemsetAsync(t + (size_t)N_NODES * D, 0, D * 4, stream);

    // ---- CSR build ----
    hipMemsetAsync(cfill, 0, (size_t)N_NODES * 4, stream);
    count_deg_k<<<(N_EDGES + 255) / 256, 256, 0, stream>>>(col, cfill);
    partial_k<<<NBLK_SCAN, 256, 0, stream>>>(cfill, psum);
    scanpart_k<<<1, 512, 0, stream>>>(psum);
    scan_scatter_k<<<NBLK_SCAN, 256, 0, stream>>>(cfill, psum, cstart);
    hipMemsetAsync(cfill, 0, (size_t)N_NODES * 4, stream);
    fill_csr_k<<<(N_EDGES + 255) / 256, 256, 0, stream>>>(row, col, cstart, cfill, esrc);

    // ---- graph bounds ----
    bounds_k<<<1, 128, 0, stream>>>(batch, gstart);

    const int ggrid = (N_NODES + BM - 1) / BM;       // 782
    const int agrid = (N_NODES + 7) / 8;             // 12500
    const int wn4 = D * D / 4;                       // 4096

    // ---- Layer 1 (x split in-register inside the gemm) ----
    split_k<<<(wn4 + 255) / 256, 256, 0, stream>>>(W1, whi, wlo, wn4);
    gemm_mfma_f32_k<<<ggrid, 256, 0, stream>>>(x, whi, wlo, b1, t, N_NODES);
    aggregate_k<<<agrid, 256, 0, stream>>>(t, cstart, esrc, hhi, hlo, 1);
    // ---- Layer 2 ----
    split_k<<<(wn4 + 255) / 256, 256, 0, stream>>>(W2, whi, wlo, wn4);
    gemm_mfma_k<<<ggrid, 256, 0, stream>>>(hhi, hlo, whi, wlo, b2, t, N_NODES);
    aggregate_k<<<agrid, 256, 0, stream>>>(t, cstart, esrc, hhi, hlo, 1);
    // ---- Layer 3 ----
    split_k<<<(wn4 + 255) / 256, 256, 0, stream>>>(W3, whi, wlo, wn4);
    gemm_mfma_k<<<ggrid, 256, 0, stream>>>(hhi, hlo, whi, wlo, b3, t, N_NODES);
    aggregate_k<<<agrid, 256, 0, stream>>>(t, cstart, esrc, hhi, hlo, 1);

    // ---- Collapsed layer 4 + pool + head (reads hhi/hlo = h3) ----
    vbeta_k<<<1, 128, 0, stream>>>(W4, b4, Wc, vbeta);
    matvec_k<<<N_NODES / 4, 256, 0, stream>>>(hhi, hlo, vbeta, s_arr);
    sagg_k<<<(N_NODES + 255) / 256, 256, 0, stream>>>(s_arr, cstart, esrc, vbeta, a_arr);
    spool_k<<<N_GRAPHS, 256, 0, stream>>>(a_arr, gstart, bc, out);
}

// Round 19
// 389.766 us; speedup vs baseline: 1.2375x; 1.0646x over previous
//
#include <hip/hip_runtime.h>
#include <hip/hip_bf16.h>

#define N_NODES 100000
#define N_EDGES 600000
#define N_GRAPHS 64
#define D 128

#define NBLK_SCAN ((N_NODES + 255) / 256)  // 391

typedef __attribute__((ext_vector_type(8))) short short8v;
typedef __attribute__((ext_vector_type(4))) float float4v;

__device__ __forceinline__ unsigned short f2bf(float f) {
    unsigned int u = __float_as_uint(f);
    return (unsigned short)((u + 0x7FFF + ((u >> 16) & 1)) >> 16);  // RNE
}
__device__ __forceinline__ float bf2f(unsigned short h) {
    return __uint_as_float(((unsigned int)h) << 16);
}

// ---------------- CSR build ----------------

__global__ void count_deg_k(const int* __restrict__ col, int* __restrict__ cnt) {
    int e = blockIdx.x * blockDim.x + threadIdx.x;
    if (e < N_EDGES) atomicAdd(&cnt[col[e]], 1);
}

__global__ __launch_bounds__(256) void partial_k(const int* __restrict__ cnt,
                                                 int* __restrict__ psum) {
    int i = blockIdx.x * 256 + threadIdx.x;
    int v = (i < N_NODES) ? cnt[i] : 0;
#pragma unroll
    for (int d = 32; d > 0; d >>= 1) v += __shfl_down(v, d, 64);
    __shared__ int ws[4];
    if ((threadIdx.x & 63) == 0) ws[threadIdx.x >> 6] = v;
    __syncthreads();
    if (threadIdx.x == 0) psum[blockIdx.x] = ws[0] + ws[1] + ws[2] + ws[3];
}

__global__ __launch_bounds__(512) void scanpart_k(int* __restrict__ psum) {
    __shared__ int ls[512];
    int t = threadIdx.x;
    int v = (t < NBLK_SCAN) ? psum[t] : 0;
    ls[t] = v;
    __syncthreads();
    for (int d = 1; d < 512; d <<= 1) {
        int u = (t >= d) ? ls[t - d] : 0;
        __syncthreads();
        ls[t] += u;
        __syncthreads();
    }
    if (t < NBLK_SCAN) psum[t] = ls[t] - v;  // exclusive
}

// also emits fillptr = copy of start (lets fill_csr skip a memset + lookup)
__global__ __launch_bounds__(256) void scan_scatter_k(const int* __restrict__ cnt,
                                                      const int* __restrict__ psum,
                                                      int* __restrict__ start,
                                                      int* __restrict__ fillptr) {
    int b = blockIdx.x, t = threadIdx.x;
    int i = b * 256 + t;
    int v = (i < N_NODES) ? cnt[i] : 0;
    __shared__ int ls[256];
    ls[t] = v;
    __syncthreads();
    for (int d = 1; d < 256; d <<= 1) {
        int u = (t >= d) ? ls[t - d] : 0;
        __syncthreads();
        ls[t] += u;
        __syncthreads();
    }
    int incl = ls[t];
    int off = psum[b];
    if (i < N_NODES) {
        int st = off + incl - v;
        start[i] = st;
        fillptr[i] = st;
    }
    if (i == N_NODES - 1) start[N_NODES] = off + incl;
}

__global__ void fill_csr_k(const int* __restrict__ row, const int* __restrict__ col,
                           int* __restrict__ fillptr, int* __restrict__ esrc) {
    int e = blockIdx.x * blockDim.x + threadIdx.x;
    if (e < N_EDGES) {
        int p = atomicAdd(&fillptr[col[e]], 1);
        esrc[p] = row[e];
    }
}

// ---------------- graph segment bounds (batch is sorted) ----------------

__global__ __launch_bounds__(128) void bounds_k(const int* __restrict__ batch,
                                                int* __restrict__ gstart) {
    int g = threadIdx.x;
    if (g > N_GRAPHS) return;
    int lo = 0, hi = N_NODES;
    while (lo < hi) {
        int mid = (lo + hi) >> 1;
        if (batch[mid] < g) lo = mid + 1; else hi = mid;
    }
    gstart[g] = lo;
}

// ---------------- all three W matrices -> (bf16 hi, bf16 lo), one launch ----------------

__global__ __launch_bounds__(256) void splitW3_k(
    const float* __restrict__ W1, const float* __restrict__ W2, const float* __restrict__ W3,
    unsigned short* __restrict__ hi0, unsigned short* __restrict__ lo0,
    unsigned short* __restrict__ hi1, unsigned short* __restrict__ lo1,
    unsigned short* __restrict__ hi2, unsigned short* __restrict__ lo2) {
    const int w = blockIdx.x >> 4;          // 0..2
    const int i = (blockIdx.x & 15) * 256 + threadIdx.x;  // 0..4095
    const float* src = (w == 0) ? W1 : (w == 1) ? W2 : W3;
    unsigned short* hi = (w == 0) ? hi0 : (w == 1) ? hi1 : hi2;
    unsigned short* lo = (w == 0) ? lo0 : (w == 1) ? lo1 : lo2;
    float4 v = reinterpret_cast<const float4*>(src)[i];
    ushort4 h, l;
    h.x = f2bf(v.x); l.x = f2bf(v.x - bf2f(h.x));
    h.y = f2bf(v.y); l.y = f2bf(v.y - bf2f(h.y));
    h.z = f2bf(v.z); l.z = f2bf(v.z - bf2f(h.z));
    h.w = f2bf(v.w); l.w = f2bf(v.w - bf2f(h.w));
    reinterpret_cast<ushort4*>(hi)[i] = h;
    reinterpret_cast<ushort4*>(lo)[i] = l;
}

// ---------------- Split-bf16 MFMA GEMM (R15 measured-good) ----------------

#define BM 128

__global__ __launch_bounds__(256) void gemm_mfma_k(
    const unsigned short* __restrict__ Ahi, const unsigned short* __restrict__ Alo,
    const unsigned short* __restrict__ Whi, const unsigned short* __restrict__ Wlo,
    const float* __restrict__ bias, float* __restrict__ out, int nrows) {
    __shared__ float swp[4][32][132];  // per-wave-private slices
    const int tid = threadIdx.x, l = tid & 63, wv = tid >> 6;
    const int bm0 = blockIdx.x * BM;
    const int g = l >> 4, li = l & 15;

    float4v acc[2][8];
#pragma unroll
    for (int rg = 0; rg < 2; ++rg)
#pragma unroll
        for (int cg = 0; cg < 8; ++cg) acc[rg][cg] = (float4v){0.f, 0.f, 0.f, 0.f};

    size_t abase[2];
#pragma unroll
    for (int rg = 0; rg < 2; ++rg)
        abase[rg] = (size_t)min(bm0 + wv * 32 + rg * 16 + li, nrows - 1) * D + g * 8;

#pragma unroll
    for (int kk = 0; kk < 4; ++kk) {
        const int k0 = kk * 32;
        short8v ah[2], al[2];
#pragma unroll
        for (int rg = 0; rg < 2; ++rg) {
            ah[rg] = *reinterpret_cast<const short8v*>(Ahi + abase[rg] + k0);
            al[rg] = *reinterpret_cast<const short8v*>(Alo + abase[rg] + k0);
        }
#pragma unroll
        for (int cg = 0; cg < 8; ++cg) {
            const size_t wb = (size_t)(cg * 16 + li) * D + g * 8 + k0;
            short8v wh = *reinterpret_cast<const short8v*>(Whi + wb);
            short8v wl = *reinterpret_cast<const short8v*>(Wlo + wb);
#pragma unroll
            for (int rg = 0; rg < 2; ++rg) {
                acc[rg][cg] = __builtin_amdgcn_mfma_f32_16x16x32_bf16(ah[rg], wh, acc[rg][cg], 0, 0, 0);
                acc[rg][cg] = __builtin_amdgcn_mfma_f32_16x16x32_bf16(al[rg], wh, acc[rg][cg], 0, 0, 0);
                acc[rg][cg] = __builtin_amdgcn_mfma_f32_16x16x32_bf16(ah[rg], wl, acc[rg][cg], 0, 0, 0);
                acc[rg][cg] = __builtin_amdgcn_mfma_f32_16x16x32_bf16(al[rg], wl, acc[rg][cg], 0, 0, 0);
            }
        }
    }

#pragma unroll
    for (int rg = 0; rg < 2; ++rg)
#pragma unroll
        for (int cg = 0; cg < 8; ++cg)
#pragma unroll
            for (int r = 0; r < 4; ++r)
                swp[wv][rg * 16 + g * 4 + r][cg * 16 + li] = acc[rg][cg][r];

    const int c4 = l & 31, rh = l >> 5;
    const float4 bias_v = *reinterpret_cast<const float4*>(&bias[c4 * 4]);
#pragma unroll
    for (int it = 0; it < 16; ++it) {
        int rowl = it * 2 + rh;
        int grow = bm0 + wv * 32 + rowl;
        if (grow < nrows) {
            float4 v = *reinterpret_cast<const float4*>(&swp[wv][rowl][c4 * 4]);
            v.x += bias_v.x; v.y += bias_v.y; v.z += bias_v.z; v.w += bias_v.w;
            *reinterpret_cast<float4*>(&out[(size_t)grow * D + c4 * 4]) = v;
        }
    }
}

// Layer-1 variant: A is f32 (x); split to bf16 hi/lo in registers.
__global__ __launch_bounds__(256) void gemm_mfma_f32_k(
    const float* __restrict__ A,
    const unsigned short* __restrict__ Whi, const unsigned short* __restrict__ Wlo,
    const float* __restrict__ bias, float* __restrict__ out, int nrows) {
    __shared__ float swp[4][32][132];
    const int tid = threadIdx.x, l = tid & 63, wv = tid >> 6;
    const int bm0 = blockIdx.x * BM;
    const int g = l >> 4, li = l & 15;

    float4v acc[2][8];
#pragma unroll
    for (int rg = 0; rg < 2; ++rg)
#pragma unroll
        for (int cg = 0; cg < 8; ++cg) acc[rg][cg] = (float4v){0.f, 0.f, 0.f, 0.f};

    size_t abase[2];
#pragma unroll
    for (int rg = 0; rg < 2; ++rg)
        abase[rg] = (size_t)min(bm0 + wv * 32 + rg * 16 + li, nrows - 1) * D + g * 8;

#pragma unroll
    for (int kk = 0; kk < 4; ++kk) {
        const int k0 = kk * 32;
        short8v ah[2], al[2];
#pragma unroll
        for (int rg = 0; rg < 2; ++rg) {
            float4 f0 = *reinterpret_cast<const float4*>(A + abase[rg] + k0);
            float4 f1 = *reinterpret_cast<const float4*>(A + abase[rg] + k0 + 4);
            float fv[8] = {f0.x, f0.y, f0.z, f0.w, f1.x, f1.y, f1.z, f1.w};
#pragma unroll
            for (int j = 0; j < 8; ++j) {
                unsigned short h = f2bf(fv[j]);
                ah[rg][j] = (short)h;
                al[rg][j] = (short)f2bf(fv[j] - bf2f(h));
            }
        }
#pragma unroll
        for (int cg = 0; cg < 8; ++cg) {
            const size_t wb = (size_t)(cg * 16 + li) * D + g * 8 + k0;
            short8v wh = *reinterpret_cast<const short8v*>(Whi + wb);
            short8v wl = *reinterpret_cast<const short8v*>(Wlo + wb);
#pragma unroll
            for (int rg = 0; rg < 2; ++rg) {
                acc[rg][cg] = __builtin_amdgcn_mfma_f32_16x16x32_bf16(ah[rg], wh, acc[rg][cg], 0, 0, 0);
                acc[rg][cg] = __builtin_amdgcn_mfma_f32_16x16x32_bf16(al[rg], wh, acc[rg][cg], 0, 0, 0);
                acc[rg][cg] = __builtin_amdgcn_mfma_f32_16x16x32_bf16(ah[rg], wl, acc[rg][cg], 0, 0, 0);
                acc[rg][cg] = __builtin_amdgcn_mfma_f32_16x16x32_bf16(al[rg], wl, acc[rg][cg], 0, 0, 0);
            }
        }
    }

#pragma unroll
    for (int rg = 0; rg < 2; ++rg)
#pragma unroll
        for (int cg = 0; cg < 8; ++cg)
#pragma unroll
            for (int r = 0; r < 4; ++r)
                swp[wv][rg * 16 + g * 4 + r][cg * 16 + li] = acc[rg][cg][r];

    const int c4 = l & 31, rh = l >> 5;
    const float4 bias_v = *reinterpret_cast<const float4*>(&bias[c4 * 4]);
#pragma unroll
    for (int it = 0; it < 16; ++it) {
        int rowl = it * 2 + rh;
        int grow = bm0 + wv * 32 + rowl;
        if (grow < nrows) {
            float4 v = *reinterpret_cast<const float4*>(&swp[wv][rowl][c4 * 4]);
            v.x += bias_v.x; v.y += bias_v.y; v.z += bias_v.z; v.w += bias_v.w;
            *reinterpret_cast<float4*>(&out[(size_t)grow * D + c4 * 4]) = v;
        }
    }
}

// ---------------- Aggregation (layers 1-2): t gather -> bf16 hi/lo ----------------
// Half-wave per node, float4 per lane (one 512B request/row), 8-deep branchless
// gather via sentinel zero row.

__global__ __launch_bounds__(256) void aggregate_k(const float* __restrict__ t,
                                                   const int* __restrict__ start,
                                                   const int* __restrict__ esrc,
                                                   unsigned short* __restrict__ ohi,
                                                   unsigned short* __restrict__ olo) {
    const int wv = threadIdx.x >> 6, l = threadIdx.x & 63;
    const int half = l >> 5, li = l & 31;
    const int node = blockIdx.x * 8 + wv * 2 + half;
    if (node >= N_NODES) return;
    const int s = start[node], e = start[node + 1];
    const size_t base = ((size_t)node << 7) + 4 * li;
    float4 acc = *reinterpret_cast<const float4*>(t + base);  // self loop
    for (int i = s; i < e; i += 8) {
        int idx[8];
#pragma unroll
        for (int j = 0; j < 8; ++j)
            idx[j] = (i + j < e) ? esrc[i + j] : N_NODES;  // sentinel = zero row
        float4 v[8];
#pragma unroll
        for (int j = 0; j < 8; ++j)
            v[j] = *reinterpret_cast<const float4*>(t + (((size_t)idx[j] << 7) + 4 * li));
        acc.x += ((v[0].x + v[1].x) + (v[2].x + v[3].x)) + ((v[4].x + v[5].x) + (v[6].x + v[7].x));
        acc.y += ((v[0].y + v[1].y) + (v[2].y + v[3].y)) + ((v[4].y + v[5].y) + (v[6].y + v[7].y));
        acc.z += ((v[0].z + v[1].z) + (v[2].z + v[3].z)) + ((v[4].z + v[5].z) + (v[6].z + v[7].z));
        acc.w += ((v[0].w + v[1].w) + (v[2].w + v[3].w)) + ((v[4].w + v[5].w) + (v[6].w + v[7].w));
    }
    acc.x = fmaxf(acc.x, 0.f);
    acc.y = fmaxf(acc.y, 0.f);
    acc.z = fmaxf(acc.z, 0.f);
    acc.w = fmaxf(acc.w, 0.f);
    ushort4 h, lo4;
    h.x = f2bf(acc.x); lo4.x = f2bf(acc.x - bf2f(h.x));
    h.y = f2bf(acc.y); lo4.y = f2bf(acc.y - bf2f(h.y));
    h.z = f2bf(acc.z); lo4.z = f2bf(acc.z - bf2f(h.z));
    h.w = f2bf(acc.w); lo4.w = f2bf(acc.w - bf2f(h.w));
    *reinterpret_cast<ushort4*>(ohi + base) = h;
    *reinterpret_cast<ushort4*>(olo + base) = lo4;
}

// ---------------- Layer-3 fused aggregate + matvec ----------------
// s[node] = relu(agg row) . v   — same gather, dot instead of 50MB write.

__global__ __launch_bounds__(256) void agg_matvec_k(const float* __restrict__ t,
                                                    const int* __restrict__ start,
                                                    const int* __restrict__ esrc,
                                                    const float* __restrict__ vbeta,
                                                    float* __restrict__ s_out) {
    const int wv = threadIdx.x >> 6, l = threadIdx.x & 63;
    const int half = l >> 5, li = l & 31;
    const int node = blockIdx.x * 8 + wv * 2 + half;
    if (node >= N_NODES) return;
    const int s = start[node], e = start[node + 1];
    const size_t base = ((size_t)node << 7) + 4 * li;
    float4 acc = *reinterpret_cast<const float4*>(t + base);  // self loop
    for (int i = s; i < e; i += 8) {
        int idx[8];
#pragma unroll
        for (int j = 0; j < 8; ++j)
            idx[j] = (i + j < e) ? esrc[i + j] : N_NODES;
        float4 v[8];
#pragma unroll
        for (int j = 0; j < 8; ++j)
            v[j] = *reinterpret_cast<const float4*>(t + (((size_t)idx[j] << 7) + 4 * li));
        acc.x += ((v[0].x + v[1].x) + (v[2].x + v[3].x)) + ((v[4].x + v[5].x) + (v[6].x + v[7].x));
        acc.y += ((v[0].y + v[1].y) + (v[2].y + v[3].y)) + ((v[4].y + v[5].y) + (v[6].y + v[7].y));
        acc.z += ((v[0].z + v[1].z) + (v[2].z + v[3].z)) + ((v[4].z + v[5].z) + (v[6].z + v[7].z));
        acc.w += ((v[0].w + v[1].w) + (v[2].w + v[3].w)) + ((v[4].w + v[5].w) + (v[6].w + v[7].w));
    }
    acc.x = fmaxf(acc.x, 0.f);
    acc.y = fmaxf(acc.y, 0.f);
    acc.z = fmaxf(acc.z, 0.f);
    acc.w = fmaxf(acc.w, 0.f);
    const float4 vv = *reinterpret_cast<const float4*>(vbeta + 4 * li);
    float p = fmaf(acc.x, vv.x, fmaf(acc.y, vv.y, fmaf(acc.z, vv.z, acc.w * vv.w)));
#pragma unroll
    for (int d = 16; d > 0; d >>= 1) p += __shfl_down(p, d, 32);  // within half-wave
    if (li == 0) s_out[node] = p;
}

// ---------------- head helpers ----------------

__global__ __launch_bounds__(128) void vbeta_k(const float* __restrict__ W4,
                                               const float* __restrict__ b4,
                                               const float* __restrict__ Wc,
                                               float* __restrict__ vbeta) {
    int k = threadIdx.x;
    float acc = 0.f;
    for (int j = 0; j < D; ++j) acc = fmaf(Wc[j], W4[j * D + k], acc);
    vbeta[k] = acc;
    __shared__ float red[128];
    red[k] = Wc[k] * b4[k];
    __syncthreads();
    for (int st = 64; st > 0; st >>= 1) {
        if (k < st) red[k] += red[k + st];
        __syncthreads();
    }
    if (k == 0) vbeta[D] = red[0];
}

__global__ __launch_bounds__(256) void sagg_k(const float* __restrict__ s,
                                              const int* __restrict__ start,
                                              const int* __restrict__ esrc,
                                              const float* __restrict__ vbeta,
                                              float* __restrict__ a) {
    int i = blockIdx.x * 256 + threadIdx.x;
    if (i >= N_NODES) return;
    int s0 = start[i], s1 = start[i + 1];
    float beta = vbeta[D];
    float acc = s[i] + (float)(1 + s1 - s0) * beta;
    for (int e = s0; e < s1; ++e) acc += s[esrc[e]];
    a[i] = acc;
}

__global__ __launch_bounds__(256) void spool_k(const float* __restrict__ a,
                                               const int* __restrict__ gstart,
                                               const float* __restrict__ bc,
                                               float* __restrict__ out) {
    int g = blockIdx.x;
    int lo = gstart[g], hi = gstart[g + 1];
    float acc = 0.f;
    for (int i = lo + threadIdx.x; i < hi; i += 256) acc += a[i];
    __shared__ float red[256];
    red[threadIdx.x] = acc;
    __syncthreads();
    for (int st = 128; st > 0; st >>= 1) {
        if (threadIdx.x < st) red[threadIdx.x] += red[threadIdx.x + st];
        __syncthreads();
    }
    if (threadIdx.x == 0) {
        float c = (float)max(hi - lo, 1);
        out[g] = 1.f / (1.f + expf(-(red[0] / c + bc[0])));
    }
}

// ---------------- Launch ----------------

extern "C" void kernel_launch(void* const* d_in, const int* in_sizes, int n_in,
                              void* d_out, int out_size, void* d_ws, size_t ws_size,
                              hipStream_t stream) {
    const float* x   = (const float*)d_in[0];
    const int* ei    = (const int*)d_in[1];
    const int* batch = (const int*)d_in[2];
    const float* W1  = (const float*)d_in[3];
    const float* b1  = (const float*)d_in[4];
    const float* W2  = (const float*)d_in[5];
    const float* b2  = (const float*)d_in[6];
    const float* W3  = (const float*)d_in[7];
    const float* b3  = (const float*)d_in[8];
    const float* W4  = (const float*)d_in[9];
    const float* b4  = (const float*)d_in[10];
    const float* Wc  = (const float*)d_in[11];
    const float* bc  = (const float*)d_in[12];
    float* out = (float*)d_out;

    const int* row = ei;             // sources
    const int* col = ei + N_EDGES;   // targets

    char* p = (char*)d_ws;
    float* t = (float*)p;            p += (size_t)(N_NODES + 1) * D * 4;  // +1 zero row
    unsigned short* hhi = (unsigned short*)p; p += (size_t)N_NODES * D * 2;
    unsigned short* hlo = (unsigned short*)p; p += (size_t)N_NODES * D * 2;
    unsigned short* w1hi = (unsigned short*)p; p += (size_t)D * D * 2;
    unsigned short* w1lo = (unsigned short*)p; p += (size_t)D * D * 2;
    unsigned short* w2hi = (unsigned short*)p; p += (size_t)D * D * 2;
    unsigned short* w2lo = (unsigned short*)p; p += (size_t)D * D * 2;
    unsigned short* w3hi = (unsigned short*)p; p += (size_t)D * D * 2;
    unsigned short* w3lo = (unsigned short*)p; p += (size_t)D * D * 2;
    int* esrc = (int*)p;             p += (size_t)(N_EDGES + 16) * 4;
    int* cstart = (int*)p;           p += ((N_NODES + 1) * 4 + 15) / 16 * 16;
    int* cfill = (int*)p;            p += (size_t)N_NODES * 4;
    int* fillptr = (int*)p;          p += (size_t)N_NODES * 4;
    int* psum = (int*)p;             p += ((NBLK_SCAN + 3) / 4) * 16;
    int* gstart = (int*)p;           p += 256;

    // tail scratch lives in hhi region (free after layer-3 gemm reads it);
    // t must stay untouched (agg_matvec gathers from it).
    float* vbeta = (float*)hhi;
    float* s_arr = (float*)hhi + 256;
    float* a_arr = (float*)hhi + 256 + N_NODES;

    // ---- zero the gather sentinel row ----
    hipMemsetAsync(t + (size_t)N_NODES * D, 0, D * 4, stream);

    // ---- weight splits (all layers, one launch) ----
    splitW3_k<<<48, 256, 0, stream>>>(W1, W2, W3, w1hi, w1lo, w2hi, w2lo, w3hi, w3lo);

    // ---- CSR build ----
    hipMemsetAsync(cfill, 0, (size_t)N_NODES * 4, stream);
    count_deg_k<<<(N_EDGES + 255) / 256, 256, 0, stream>>>(col, cfill);
    partial_k<<<NBLK_SCAN, 256, 0, stream>>>(cfill, psum);
    scanpart_k<<<1, 512, 0, stream>>>(psum);
    scan_scatter_k<<<NBLK_SCAN, 256, 0, stream>>>(cfill, psum, cstart, fillptr);
    fill_csr_k<<<(N_EDGES + 255) / 256, 256, 0, stream>>>(row, col, fillptr, esrc);

    // ---- graph bounds ----
    bounds_k<<<1, 128, 0, stream>>>(batch, gstart);

    const int ggrid = (N_NODES + BM - 1) / BM;       // 782
    const int agrid = (N_NODES + 7) / 8;             // 12500

    // ---- Layer 1 (x split in-register inside the gemm) ----
    gemm_mfma_f32_k<<<ggrid, 256, 0, stream>>>(x, w1hi, w1lo, b1, t, N_NODES);
    aggregate_k<<<agrid, 256, 0, stream>>>(t, cstart, esrc, hhi, hlo);
    // ---- Layer 2 ----
    gemm_mfma_k<<<ggrid, 256, 0, stream>>>(hhi, hlo, w2hi, w2lo, b2, t, N_NODES);
    aggregate_k<<<agrid, 256, 0, stream>>>(t, cstart, esrc, hhi, hlo);
    // ---- Layer 3 (gemm only; aggregate fused with matvec below) ----
    gemm_mfma_k<<<ggrid, 256, 0, stream>>>(hhi, hlo, w3hi, w3lo, b3, t, N_NODES);

    // ---- Collapsed layer 4 + pool + head ----
    vbeta_k<<<1, 128, 0, stream>>>(W4, b4, Wc, vbeta);       // writes hhi region (free now)
    agg_matvec_k<<<agrid, 256, 0, stream>>>(t, cstart, esrc, vbeta, s_arr);
    sagg_k<<<(N_NODES + 255) / 256, 256, 0, stream>>>(s_arr, cstart, esrc, vbeta, a_arr);
    spool_k<<<N_GRAPHS, 256, 0, stream>>>(a_arr, gstart, bc, out);
}